// Round 10
// baseline (618.592 us; speedup 1.0000x reference)
//
#include <hip/hip_runtime.h>
#include <hip/hip_bf16.h>

#define B_  16
#define C_  1024
#define NP_ 512
#define DM_ 512
#define H_  8
#define D_  64
#define BC_ 16384

#define PAVG_STRIDE 17
#define NBMAX 4          // S-chunk 128 MB; NBMAX=2 regressed (launch tails > L3 win)
#define FLDS 40          // padded LDS row stride (halfs) for 32-K tiles
#define FLDS2 72         // padded LDS row stride (halfs) for the 64-K score tile

typedef unsigned long long ull;
typedef unsigned short u16;
using short8 = __attribute__((ext_vector_type(8))) short;
using half8  = __attribute__((ext_vector_type(8))) _Float16;
using f32x4  = __attribute__((ext_vector_type(4))) float;

__device__ __forceinline__ u16 f2bf(float x) {
    __hip_bfloat16 h = __float2bfloat16(x);
    return *reinterpret_cast<u16*>(&h);
}
__device__ __forceinline__ float bf2f(u16 v) {
    return __uint_as_float(((unsigned)v) << 16);
}
__device__ __forceinline__ u16 h_bits(_Float16 h) {
    return *reinterpret_cast<u16*>(&h);
}

// ==================== split-f16 MFMA GEMM core ====================
// C(fp32) = A * B^T computed as 4 f16 MFMA passes over (hi+lo) splits.
// Each f16 x f16 product is exact in the fp32 accumulator -> fp32-class
// precision (~2^-23); required: min rank-16/17 gap over 16k avg-rows ~1e-7,
// so do NOT drop the lo*lo pass (3-pass = 2^-22 risks an A-flip).

__device__ __forceinline__ void hsplit_stage(const u16* __restrict__ Ah, const u16* __restrict__ Al,
    const u16* __restrict__ Bh, const u16* __restrict__ Bl,
    int lda, int ldb, int row0, int col0, int k0,
    u16* __restrict__ sAh, u16* __restrict__ sAl,
    u16* __restrict__ sBh, u16* __restrict__ sBl, int tid)
{
#pragma unroll
    for (int rep = 0; rep < 2; ++rep) {
        const int c = tid + rep * 256;
        const int row = c >> 2, kq = (c & 3) * 8;
        const size_t ga = (size_t)(row0 + row) * lda + k0 + kq;
        const size_t gb = (size_t)(col0 + row) * ldb + k0 + kq;
        *(uint4*)(&sAh[row * FLDS + kq]) = *(const uint4*)(Ah + ga);
        *(uint4*)(&sAl[row * FLDS + kq]) = *(const uint4*)(Al + ga);
        *(uint4*)(&sBh[row * FLDS + kq]) = *(const uint4*)(Bh + gb);
        *(uint4*)(&sBl[row * FLDS + kq]) = *(const uint4*)(Bl + gb);
    }
}

__device__ __forceinline__ void hsplit_compute(const u16* __restrict__ sAh, const u16* __restrict__ sAl,
    const u16* __restrict__ sBh, const u16* __restrict__ sBl,
    int lane, int wm, int wn, f32x4 (&acc)[4][4])
{
    const int q8 = (lane >> 4) * 8, l16 = lane & 15;
    half8 bh[4], bl_[4];
#pragma unroll
    for (int nt = 0; nt < 4; ++nt) {
        const int o = (wn * 64 + nt * 16 + l16) * FLDS + q8;
        bh[nt]  = *(const half8*)(&sBh[o]);
        bl_[nt] = *(const half8*)(&sBl[o]);
    }
#pragma unroll
    for (int mt = 0; mt < 4; ++mt) {
        const int o = (wm * 64 + mt * 16 + l16) * FLDS + q8;
        const half8 ah = *(const half8*)(&sAh[o]);
        const half8 al = *(const half8*)(&sAl[o]);
#pragma unroll
        for (int nt = 0; nt < 4; ++nt) {
            acc[mt][nt] = __builtin_amdgcn_mfma_f32_16x16x32_f16(ah, bh[nt],  acc[mt][nt], 0, 0, 0);
            acc[mt][nt] = __builtin_amdgcn_mfma_f32_16x16x32_f16(al, bh[nt],  acc[mt][nt], 0, 0, 0);
            acc[mt][nt] = __builtin_amdgcn_mfma_f32_16x16x32_f16(ah, bl_[nt], acc[mt][nt], 0, 0, 0);
            acc[mt][nt] = __builtin_amdgcn_mfma_f32_16x16x32_f16(al, bl_[nt], acc[mt][nt], 0, 0, 0);
        }
    }
}

// ==================== convert kernels ====================

// merged weight convert: y=0 Wo->bf16, y=1 Wv->bf16, y=2 Wq->f16 hi/lo, y=3 Wk->f16 hi/lo
__global__ __launch_bounds__(256) void w_convert(
    const float* __restrict__ Wo, const float* __restrict__ Wv,
    const float* __restrict__ Wq, const float* __restrict__ Wk,
    u16* __restrict__ Wob, u16* __restrict__ Wvb,
    u16* __restrict__ Wqh, u16* __restrict__ Wql,
    u16* __restrict__ Wkh, u16* __restrict__ Wkl)
{
    const int i = (blockIdx.x * 256 + threadIdx.x) * 4;
    const int y = blockIdx.y;
    if (y < 2) {
        const float* X = (y == 0) ? Wo : Wv;
        u16* Dp = (y == 0) ? Wob : Wvb;
        const float4 v = *(const float4*)(X + i);
        ushort4 o;
        o.x = f2bf(v.x); o.y = f2bf(v.y); o.z = f2bf(v.z); o.w = f2bf(v.w);
        *(ushort4*)(Dp + i) = o;
    } else {
        const float* X = (y == 2) ? Wq : Wk;
        u16* Hh = (y == 2) ? Wqh : Wkh;
        u16* Hl = (y == 2) ? Wql : Wkl;
        const float4 v = *(const float4*)(X + i);
        ushort4 oh, ol;
        {
            _Float16 h = (_Float16)v.x; oh.x = h_bits(h); ol.x = h_bits((_Float16)(v.x - (float)h));
        }{
            _Float16 h = (_Float16)v.y; oh.y = h_bits(h); ol.y = h_bits((_Float16)(v.y - (float)h));
        }{
            _Float16 h = (_Float16)v.z; oh.z = h_bits(h); ol.z = h_bits((_Float16)(v.z - (float)h));
        }{
            _Float16 h = (_Float16)v.w; oh.w = h_bits(h); ol.w = h_bits((_Float16)(v.w - (float)h));
        }
        *(ushort4*)(Hh + i) = oh;
        *(ushort4*)(Hl + i) = ol;
    }
}

// Mi -> bf16 (for V path) + f16 hi/lo (for Q/K path) in one read pass
__global__ __launch_bounds__(256) void mi_convert(const float* __restrict__ X,
    u16* __restrict__ Bb, u16* __restrict__ Hh, u16* __restrict__ Hl)
{
    const int i = (blockIdx.x * 256 + threadIdx.x) * 4;
    const float4 v = *(const float4*)(X + i);
    ushort4 ob, oh, ol;
    {
        _Float16 h = (_Float16)v.x; ob.x = f2bf(v.x); oh.x = h_bits(h); ol.x = h_bits((_Float16)(v.x - (float)h));
    }{
        _Float16 h = (_Float16)v.y; ob.y = f2bf(v.y); oh.y = h_bits(h); ol.y = h_bits((_Float16)(v.y - (float)h));
    }{
        _Float16 h = (_Float16)v.z; ob.z = f2bf(v.z); oh.z = h_bits(h); ol.z = h_bits((_Float16)(v.z - (float)h));
    }{
        _Float16 h = (_Float16)v.w; ob.w = f2bf(v.w); oh.w = h_bits(h); ol.w = h_bits((_Float16)(v.w - (float)h));
    }
    *(ushort4*)(Bb + i) = ob;
    *(ushort4*)(Hh + i) = oh;
    *(ushort4*)(Hl + i) = ol;
}

// ==================== kernel 1: Q/K projections via split-f16 MFMA ====================
__global__ __launch_bounds__(256) void qk_gemm_mfma(
    const u16* __restrict__ Mih, const u16* __restrict__ Mil,
    const u16* __restrict__ Wqh, const u16* __restrict__ Wql,
    const u16* __restrict__ Wkh, const u16* __restrict__ Wkl,
    u16* __restrict__ Qh, u16* __restrict__ Ql,
    u16* __restrict__ Kh, u16* __restrict__ Kl)
{
    __shared__ u16 sAh[128 * FLDS];
    __shared__ u16 sAl[128 * FLDS];
    __shared__ u16 sBh[128 * FLDS];
    __shared__ u16 sBl[128 * FLDS];

    const int tid = threadIdx.x, lane = tid & 63, w = tid >> 6;
    const int wm = w >> 1, wn = w & 1;
    const int z = blockIdx.z;
    const u16* Bh = z ? Wkh : Wqh;
    const u16* Bl = z ? Wkl : Wql;
    u16* outH = z ? Kh : Qh;
    u16* outL = z ? Kl : Ql;
    const int row0 = blockIdx.x * 128, col0 = blockIdx.y * 128;

    f32x4 acc[4][4];
#pragma unroll
    for (int mt = 0; mt < 4; ++mt)
#pragma unroll
        for (int nt = 0; nt < 4; ++nt)
            acc[mt][nt] = (f32x4){0.f, 0.f, 0.f, 0.f};

    for (int k0 = 0; k0 < NP_; k0 += 32) {
        hsplit_stage(Mih, Mil, Bh, Bl, NP_, NP_, row0, col0, k0, sAh, sAl, sBh, sBl, tid);
        __syncthreads();
        hsplit_compute(sAh, sAl, sBh, sBl, lane, wm, wn, acc);
        __syncthreads();
    }

    const int quad = lane >> 4, l16 = lane & 15;
#pragma unroll
    for (int mt = 0; mt < 4; ++mt)
#pragma unroll
        for (int nt = 0; nt < 4; ++nt) {
            const int n = col0 + wn * 64 + nt * 16 + l16;
            const int hh = n >> 6, dd = n & 63;
#pragma unroll
            for (int reg = 0; reg < 4; ++reg) {
                const int m = row0 + wm * 64 + mt * 16 + quad * 4 + reg;
                const int bl = m >> 10, c = m & 1023;
                const size_t idx = ((size_t)(bl * 8 + hh) * C_ + c) * D_ + dd;
                const float v = acc[mt][nt][reg];
                const _Float16 vh = (_Float16)v;
                outH[idx] = h_bits(vh);
                outL[idx] = h_bits((_Float16)(v - (float)vh));
            }
        }
}

// ==================== kernel 2: scores via split-f16 MFMA, single-stage BK=64 ====================
__global__ __launch_bounds__(256) void score_gemm_mfma(
    const u16* __restrict__ Qh, const u16* __restrict__ Ql,
    const u16* __restrict__ Kh, const u16* __restrict__ Kl,
    float* __restrict__ S)
{
    __shared__ u16 sAh[128 * FLDS2];
    __shared__ u16 sAl[128 * FLDS2];
    __shared__ u16 sBh[128 * FLDS2];
    __shared__ u16 sBl[128 * FLDS2];

    const int tid = threadIdx.x, lane = tid & 63, w = tid >> 6;
    const int wm = w >> 1, wn = w & 1;
    const int z = blockIdx.z;
    const size_t off = (size_t)z * C_ * D_;
    const u16* Ah = Qh + off;  const u16* Al = Ql + off;
    const u16* Bh = Kh + off;  const u16* Bl = Kl + off;
    float* Cp = S + (size_t)z * C_ * C_;
    const int row0 = blockIdx.x * 128, col0 = blockIdx.y * 128;

    f32x4 acc[4][4];
#pragma unroll
    for (int mt = 0; mt < 4; ++mt)
#pragma unroll
        for (int nt = 0; nt < 4; ++nt)
            acc[mt][nt] = (f32x4){0.f, 0.f, 0.f, 0.f};

    // stage all K=64 (8 uint4-chunks per 128-B row; 1024 chunks per plane)
#pragma unroll
    for (int rep = 0; rep < 4; ++rep) {
        const int c = tid + rep * 256;
        const int row = c >> 3, kq = (c & 7) * 8;
        const size_t ga = (size_t)(row0 + row) * D_ + kq;
        const size_t gb = (size_t)(col0 + row) * D_ + kq;
        *(uint4*)(&sAh[row * FLDS2 + kq]) = *(const uint4*)(Ah + ga);
        *(uint4*)(&sAl[row * FLDS2 + kq]) = *(const uint4*)(Al + ga);
        *(uint4*)(&sBh[row * FLDS2 + kq]) = *(const uint4*)(Bh + gb);
        *(uint4*)(&sBl[row * FLDS2 + kq]) = *(const uint4*)(Bl + gb);
    }
    __syncthreads();

    const int q8 = (lane >> 4) * 8, l16 = lane & 15;
#pragma unroll
    for (int ks = 0; ks < 2; ++ks) {
        const int kof = ks * 32 + q8;
        half8 bh[4], bl_[4];
#pragma unroll
        for (int nt = 0; nt < 4; ++nt) {
            const int o = (wn * 64 + nt * 16 + l16) * FLDS2 + kof;
            bh[nt]  = *(const half8*)(&sBh[o]);
            bl_[nt] = *(const half8*)(&sBl[o]);
        }
#pragma unroll
        for (int mt = 0; mt < 4; ++mt) {
            const int o = (wm * 64 + mt * 16 + l16) * FLDS2 + kof;
            const half8 ah = *(const half8*)(&sAh[o]);
            const half8 al = *(const half8*)(&sAl[o]);
#pragma unroll
            for (int nt = 0; nt < 4; ++nt) {
                acc[mt][nt] = __builtin_amdgcn_mfma_f32_16x16x32_f16(ah, bh[nt],  acc[mt][nt], 0, 0, 0);
                acc[mt][nt] = __builtin_amdgcn_mfma_f32_16x16x32_f16(al, bh[nt],  acc[mt][nt], 0, 0, 0);
                acc[mt][nt] = __builtin_amdgcn_mfma_f32_16x16x32_f16(ah, bl_[nt], acc[mt][nt], 0, 0, 0);
                acc[mt][nt] = __builtin_amdgcn_mfma_f32_16x16x32_f16(al, bl_[nt], acc[mt][nt], 0, 0, 0);
            }
        }
    }

    const int quad = lane >> 4;
#pragma unroll
    for (int mt = 0; mt < 4; ++mt)
#pragma unroll
        for (int nt = 0; nt < 4; ++nt) {
            const int n = col0 + wn * 64 + nt * 16 + l16;
#pragma unroll
            for (int reg = 0; reg < 4; ++reg) {
                const int m = row0 + wm * 64 + mt * 16 + quad * 4 + reg;
                Cp[(size_t)m * C_ + n] = acc[mt][nt][reg] * 0.125f;
            }
        }
}

// ==================== kernel 1b: V projection via bf16 MFMA ====================
__global__ __launch_bounds__(256) void v_gemm_mfma(const u16* __restrict__ Mib,
    const u16* __restrict__ Wvb, u16* __restrict__ Vb)
{
    __shared__ u16 As[128 * FLDS];
    __shared__ u16 Bs[128 * FLDS];
    const int tid = threadIdx.x, lane = tid & 63, w = tid >> 6;
    const int wm = w >> 1, wn = w & 1;
    const int row0 = blockIdx.x * 128, col0 = blockIdx.y * 128;

    f32x4 acc[4][4];
#pragma unroll
    for (int mt = 0; mt < 4; ++mt)
#pragma unroll
        for (int nt = 0; nt < 4; ++nt)
            acc[mt][nt] = (f32x4){0.f, 0.f, 0.f, 0.f};

    const int q8 = (lane >> 4) * 8, l16 = lane & 15;
    for (int k0 = 0; k0 < NP_; k0 += 32) {
#pragma unroll
        for (int rep = 0; rep < 2; ++rep) {
            const int c = tid + rep * 256;
            const int row = c >> 2, kq = (c & 3) * 8;
            *(uint4*)(&As[row * FLDS + kq]) = *(const uint4*)(Mib + (size_t)(row0 + row) * NP_ + k0 + kq);
            *(uint4*)(&Bs[row * FLDS + kq]) = *(const uint4*)(Wvb + (size_t)(col0 + row) * NP_ + k0 + kq);
        }
        __syncthreads();
        short8 a[4], bfr[4];
#pragma unroll
        for (int mt = 0; mt < 4; ++mt)
            a[mt] = *(const short8*)(&As[(wm * 64 + mt * 16 + l16) * FLDS + q8]);
#pragma unroll
        for (int nt = 0; nt < 4; ++nt)
            bfr[nt] = *(const short8*)(&Bs[(wn * 64 + nt * 16 + l16) * FLDS + q8]);
#pragma unroll
        for (int mt = 0; mt < 4; ++mt)
#pragma unroll
            for (int nt = 0; nt < 4; ++nt)
                acc[mt][nt] = __builtin_amdgcn_mfma_f32_16x16x32_bf16(a[mt], bfr[nt], acc[mt][nt], 0, 0, 0);
        __syncthreads();
    }
    const int quad = lane >> 4;
#pragma unroll
    for (int mt = 0; mt < 4; ++mt)
#pragma unroll
        for (int nt = 0; nt < 4; ++nt) {
            const int n = col0 + wn * 64 + nt * 16 + l16;
#pragma unroll
            for (int reg = 0; reg < 4; ++reg) {
                const int m = row0 + wm * 64 + mt * 16 + quad * 4 + reg;
                Vb[(size_t)m * DM_ + n] = f2bf(acc[mt][nt][reg]);
            }
        }
}

// ==================== top-k machinery ====================
// key = (monotone(value) << 32) | (1023 - j): distinct keys, ties -> smallest j
// (matches jax.lax.top_k). tau via dual-interleaved ballot radix TRUNCATED at
// bit 12: tau' <= true 16th-largest lane-max, so the candidate set is a
// superset of the guaranteed-correct one -- the downstream exact sort keeps
// selection exact. Saves 12 of 32 serial radix steps. 32-wide bitonic fast
// path when candidates <= 32 (the common case).

__device__ __forceinline__ ull pack1(float f, int j) {
    unsigned b = __float_as_uint(f);
    unsigned u = b ^ ((unsigned)((int)b >> 31) | 0x80000000u);
    return ((ull)u << 32) | (unsigned)(1023 - j);
}
__device__ __forceinline__ float unpack_val(ull e) {
    unsigned u = (unsigned)(e >> 32);
    unsigned b = u ^ ((u & 0x80000000u) ? 0x80000000u : 0xFFFFFFFFu);
    return __uint_as_float(b);
}
__device__ __forceinline__ int unpack_j(ull e) {
    return 1023 - (int)(e & 0xFFFFFFFFu);
}
__device__ __forceinline__ unsigned mono32(float f) {
    unsigned b = __float_as_uint(f);
    return b ^ ((unsigned)((int)b >> 31) | 0x80000000u);
}
__device__ __forceinline__ float mono32_inv(unsigned u) {
    unsigned b = u ^ ((u & 0x80000000u) ? 0x80000000u : 0xFFFFFFFFu);
    return __uint_as_float(b);
}

// truncated (20-step) lower bound on the 16th-largest of the 64 lane keys
__device__ __forceinline__ unsigned radix16_u32(unsigned k)
{
    unsigned p = 0u;
#pragma unroll
    for (int b = 31; b >= 12; --b) {
        const unsigned t = p | (1u << b);
        if (__popcll(__ballot(k >= t)) >= 16) p = t;
    }
    return p;
}

// dual-interleaved truncated version: both chains advance each iteration
__device__ __forceinline__ void radix16_dual_u32(unsigned kA, unsigned kB,
                                                 unsigned &pA, unsigned &pB)
{
    pA = 0u; pB = 0u;
#pragma unroll
    for (int b = 31; b >= 12; --b) {
        const unsigned tA = pA | (1u << b);
        const unsigned tB = pB | (1u << b);
        const ull mA = __ballot(kA >= tA);
        const ull mB = __ballot(kB >= tB);
        if (__popcll(mA) >= 16) pA = tA;
        if (__popcll(mB) >= 16) pB = tB;
    }
}

// ---- single-chain top-16 (avg-scores wave). Radix tau + bitonic cand sort. ----
__device__ __forceinline__ void topk16_fast(float (&f)[16], const int lane,
                                            ull* candw, ull (&out)[16])
{
    float mv = f[0];
#pragma unroll
    for (int r = 1; r < 16; ++r) mv = fmaxf(mv, f[r]);
    const float tau = mono32_inv(radix16_u32(mono32(mv)));

    unsigned msk = 0u;
#pragma unroll
    for (int r = 0; r < 16; ++r) msk |= (f[r] >= tau) ? (1u << r) : 0u;
    const int cnt = __popc(msk);
    int incl = cnt;
#pragma unroll
    for (int off = 1; off < 64; off <<= 1) {
        const int t = __shfl_up(incl, off);
        incl += (lane >= off) ? t : 0;
    }
    const int total = __shfl(incl, 63);

    if (total <= 64) {
        int ofs = incl - cnt;
        unsigned m = msk;
        while (m) {
            const int r = __ffs(m) - 1;
            m &= m - 1;
            candw[ofs++] = pack1(f[r], (lane << 4) + r);
        }
        ull e = candw[lane];
        if (lane >= total) e = 0ull;
        if (total <= 32) {
#pragma unroll
            for (int k = 2; k <= 32; k <<= 1) {
#pragma unroll
                for (int j = k >> 1; j > 0; j >>= 1) {
                    const ull p = __shfl_xor(e, j);
                    const bool kmax = ((lane & k) == 0) == ((lane & j) == 0);
                    if ((p > e) == kmax) e = p;
                }
            }
        } else {
#pragma unroll
            for (int k = 2; k <= 64; k <<= 1) {
#pragma unroll
                for (int j = k >> 1; j > 0; j >>= 1) {
                    const ull p = __shfl_xor(e, j);
                    const bool kmax = ((lane & k) == 0) == ((lane & j) == 0);
                    if ((p > e) == kmax) e = p;
                }
            }
        }
#pragma unroll
        for (int t = 0; t < 16; ++t) out[t] = __shfl(e, t);
    } else {
        for (int it = 0; it < 16; ++it) {
            float bv = f[0]; int bj = lane << 4;
#pragma unroll
            for (int r = 1; r < 16; ++r)
                if (f[r] > bv) { bv = f[r]; bj = (lane << 4) + r; }
#pragma unroll
            for (int off = 32; off >= 1; off >>= 1) {
                const float ov = __shfl_xor(bv, off);
                const int   oj = __shfl_xor(bj, off);
                if (ov > bv || (ov == bv && oj < bj)) { bv = ov; bj = oj; }
            }
            out[it] = pack1(bv, bj);
            if ((bj >> 4) == lane) f[bj & 15] = -3.402823466e38f;
        }
    }
}

// ---- fallback serial selection; lane t (t<16) ends holding rank-t element ----
__device__ __forceinline__ ull topk16_serial(float (&f)[16], const int lane)
{
    ull e = 0ull;
    for (int it = 0; it < 16; ++it) {
        float bv = f[0]; int bj = lane << 4;
#pragma unroll
        for (int r = 1; r < 16; ++r)
            if (f[r] > bv) { bv = f[r]; bj = (lane << 4) + r; }
#pragma unroll
        for (int off = 32; off >= 1; off >>= 1) {
            const float ov = __shfl_xor(bv, off);
            const int   oj = __shfl_xor(bj, off);
            if (ov > bv || (ov == bv && oj < bj)) { bv = ov; bj = oj; }
        }
        if (lane == it) e = pack1(bv, bj);
        if ((bj >> 4) == lane) f[bj & 15] = -3.402823466e38f;
    }
    return e;
}

// ---- dual-chain top-16 (round-2/4 proven structure; truncated dual radix tau;
// 32-wide bitonic fast path when both chains have <=32 candidates) ----
__device__ __forceinline__ void topk16_dual(float (&fA)[16], float (&fB)[16],
                                            const int lane, ull* cwA, ull* cwB,
                                            ull &eA, ull &eB)
{
    float mA = fA[0], mB = fB[0];
#pragma unroll
    for (int r = 1; r < 16; ++r) { mA = fmaxf(mA, fA[r]); mB = fmaxf(mB, fB[r]); }
    unsigned pA, pB;
    radix16_dual_u32(mono32(mA), mono32(mB), pA, pB);
    const float tauA = mono32_inv(pA);
    const float tauB = mono32_inv(pB);

    unsigned mskA = 0u, mskB = 0u;
#pragma unroll
    for (int r = 0; r < 16; ++r) {
        mskA |= (fA[r] >= tauA) ? (1u << r) : 0u;
        mskB |= (fB[r] >= tauB) ? (1u << r) : 0u;
    }
    const int cntA = __popc(mskA), cntB = __popc(mskB);
    int inclA = cntA, inclB = cntB;
#pragma unroll
    for (int off = 1; off < 64; off <<= 1) {
        const int tA = __shfl_up(inclA, off);
        const int tB = __shfl_up(inclB, off);
        inclA += (lane >= off) ? tA : 0;
        inclB += (lane >= off) ? tB : 0;
    }
    const int totalA = __shfl(inclA, 63);
    const int totalB = __shfl(inclB, 63);

    if (totalA <= 64) {
        int ofs = inclA - cntA;
        unsigned m = mskA;
        while (m) {
            const int r = __ffs(m) - 1;
            m &= m - 1;
            cwA[ofs++] = pack1(fA[r], (lane << 4) + r);
        }
    }
    if (totalB <= 64) {
        int ofs = inclB - cntB;
        unsigned m = mskB;
        while (m) {
            const int r = __ffs(m) - 1;
            m &= m - 1;
            cwB[ofs++] = pack1(fB[r], (lane << 4) + r);
        }
    }
    eA = (totalA <= 64 && lane < totalA) ? cwA[lane] : 0ull;
    eB = (totalB <= 64 && lane < totalB) ? cwB[lane] : 0ull;
    if (totalA <= 32 && totalB <= 32) {
#pragma unroll
        for (int k = 2; k <= 32; k <<= 1) {
#pragma unroll
            for (int j = k >> 1; j > 0; j >>= 1) {
                const ull pAx = __shfl_xor(eA, j);
                const ull pBx = __shfl_xor(eB, j);
                const bool kmax = ((lane & k) == 0) == ((lane & j) == 0);
                if ((pAx > eA) == kmax) eA = pAx;
                if ((pBx > eB) == kmax) eB = pBx;
            }
        }
    } else {
#pragma unroll
        for (int k = 2; k <= 64; k <<= 1) {
#pragma unroll
            for (int j = k >> 1; j > 0; j >>= 1) {
                const ull pAx = __shfl_xor(eA, j);
                const ull pBx = __shfl_xor(eB, j);
                const bool kmax = ((lane & k) == 0) == ((lane & j) == 0);
                if ((pAx > eA) == kmax) eA = pAx;
                if ((pBx > eB) == kmax) eB = pBx;
            }
        }
    }
    if (totalA > 64) eA = topk16_serial(fA, lane);
    if (totalB > 64) eB = topk16_serial(fB, lane);
}

__device__ __forceinline__ void attn_out(const ull e, const u16* __restrict__ V,
                                         int bl, int i, int h, int lane,
                                         u16* __restrict__ O)
{
    float vals[16]; int jl[16];
#pragma unroll
    for (int t = 0; t < 16; ++t) {
        const ull et = __shfl(e, t);
        vals[t] = unpack_val(et);
        jl[t]   = unpack_j(et);
    }
    const float mx = vals[0];
    float wv[16];
    float Z = 0.0f;
#pragma unroll
    for (int t = 0; t < 16; ++t) { wv[t] = __expf(vals[t] - mx); Z += wv[t]; }
    const float inv = 1.0f / Z;
#pragma unroll
    for (int t = 0; t < 16; ++t) wv[t] *= inv;
    float o = 0.0f;
#pragma unroll
    for (int t = 0; t < 16; ++t)
        o = fmaf(wv[t], bf2f(V[((size_t)(bl * C_ + jl[t])) * DM_ + h * D_ + lane]), o);
    O[((size_t)(bl * C_ + i)) * DM_ + h * D_ + lane] = f2bf(o);
}

// ---- kernel 3: per-row topk + softmax + sparse AV(bf16) + A output ----
// 320 threads: waves 0-3 handle the 8 attention heads (dual-chain, 2 each);
// wave 4 does the avg-scores top-16 concurrently, writes A row directly.
__global__ __launch_bounds__(320) void topk_attn(const float* __restrict__ S,
    const u16* __restrict__ V, u16* __restrict__ O,
    float* __restrict__ Aout, int b0)
{
    __shared__ float pavg[4 * 64 * PAVG_STRIDE];
    __shared__ ull   cand[4][2][64];
    __shared__ ull   candA[64];

    const int tid = threadIdx.x, lane = tid & 63, w = tid >> 6;
    const int rb = blockIdx.x, bl = rb >> 10, i = rb & 1023;
    const int b = b0 + bl;

    float f1[16], f2[16];
    if (w < 4) {
        const float* r1 = S + ((size_t)(bl * 8 + w) * C_ + i) * C_ + lane * 16;
        const float* r2 = S + ((size_t)(bl * 8 + w + 4) * C_ + i) * C_ + lane * 16;
#pragma unroll
        for (int q = 0; q < 4; ++q) {
            const float4 x = *(const float4*)(r1 + q * 4);
            f1[q * 4 + 0] = x.x; f1[q * 4 + 1] = x.y; f1[q * 4 + 2] = x.z; f1[q * 4 + 3] = x.w;
            const float4 y = *(const float4*)(r2 + q * 4);
            f2[q * 4 + 0] = y.x; f2[q * 4 + 1] = y.y; f2[q * 4 + 2] = y.z; f2[q * 4 + 3] = y.w;
        }
        float* pw = pavg + w * 64 * PAVG_STRIDE + lane * PAVG_STRIDE;
#pragma unroll
        for (int r = 0; r < 16; ++r) pw[r] = f1[r] + f2[r];
    }
    __syncthreads();

    if (w < 4) {
        ull eA, eB;
        topk16_dual(f1, f2, lane, cand[w][0], cand[w][1], eA, eB);
        attn_out(eA, V, bl, i, w,     lane, O);
        attn_out(eB, V, bl, i, w + 4, lane, O);
    } else {
        float fa[16];
#pragma unroll
        for (int r = 0; r < 16; ++r) {
            fa[r] = pavg[0 * 64 * PAVG_STRIDE + lane * PAVG_STRIDE + r]
                  + pavg[1 * 64 * PAVG_STRIDE + lane * PAVG_STRIDE + r]
                  + pavg[2 * 64 * PAVG_STRIDE + lane * PAVG_STRIDE + r]
                  + pavg[3 * 64 * PAVG_STRIDE + lane * PAVG_STRIDE + r];
        }
        ull top[16];
        topk16_fast(fa, lane, candA, top);
        unsigned mybits = 0u;
#pragma unroll
        for (int t = 0; t < 16; ++t) {
            const int j = unpack_j(top[t]);
            if ((j >> 4) == lane) mybits |= 1u << (j & 15);
        }
        float* arow = Aout + ((size_t)(b * C_ + i)) * C_ + lane * 16;
#pragma unroll
        for (int q = 0; q < 4; ++q) {
            float4 o4;
            o4.x = ((mybits >> (q * 4 + 0)) & 1u) ? 1.0f : 0.0f;
            o4.y = ((mybits >> (q * 4 + 1)) & 1u) ? 1.0f : 0.0f;
            o4.z = ((mybits >> (q * 4 + 2)) & 1u) ? 1.0f : 0.0f;
            o4.w = ((mybits >> (q * 4 + 3)) & 1u) ? 1.0f : 0.0f;
            *(float4*)(arow + q * 4) = o4;
        }
    }
}

// ---- kernel 4: MFMA bf16: delta = O @ Wo^T + bo ; M_tilde = M + gate*delta ----
__global__ __launch_bounds__(256) void final_gemm_mfma(const u16* __restrict__ O,
    const u16* __restrict__ Wob, const float* __restrict__ Mi,
    const float* __restrict__ bo, const float* __restrict__ gatep,
    float* __restrict__ out)
{
    __shared__ u16 As[128 * FLDS];
    __shared__ u16 Bs[128 * FLDS];
    const int tid = threadIdx.x, lane = tid & 63, w = tid >> 6;
    const int wm = w >> 1, wn = w & 1;
    const int row0 = blockIdx.x * 128, col0 = blockIdx.y * 128;

    f32x4 acc[4][4];
#pragma unroll
    for (int mt = 0; mt < 4; ++mt)
#pragma unroll
        for (int nt = 0; nt < 4; ++nt)
            acc[mt][nt] = (f32x4){0.f, 0.f, 0.f, 0.f};

    const int q8 = (lane >> 4) * 8, l16 = lane & 15;
    for (int k0 = 0; k0 < DM_; k0 += 32) {
#pragma unroll
        for (int rep = 0; rep < 2; ++rep) {
            const int c = tid + rep * 256;
            const int row = c >> 2, kq = (c & 3) * 8;
            *(uint4*)(&As[row * FLDS + kq]) = *(const uint4*)(O   + (size_t)(row0 + row) * DM_ + k0 + kq);
            *(uint4*)(&Bs[row * FLDS + kq]) = *(const uint4*)(Wob + (size_t)(col0 + row) * DM_ + k0 + kq);
        }
        __syncthreads();
        short8 a[4], bfr[4];
#pragma unroll
        for (int mt = 0; mt < 4; ++mt)
            a[mt] = *(const short8*)(&As[(wm * 64 + mt * 16 + l16) * FLDS + q8]);
#pragma unroll
        for (int nt = 0; nt < 4; ++nt)
            bfr[nt] = *(const short8*)(&Bs[(wn * 64 + nt * 16 + l16) * FLDS + q8]);
#pragma unroll
        for (int mt = 0; mt < 4; ++mt)
#pragma unroll
            for (int nt = 0; nt < 4; ++nt)
                acc[mt][nt] = __builtin_amdgcn_mfma_f32_16x16x32_bf16(a[mt], bfr[nt], acc[mt][nt], 0, 0, 0);
        __syncthreads();
    }

    const float g = gatep[0];
    const int quad = lane >> 4;
#pragma unroll
    for (int mt = 0; mt < 4; ++mt) {
#pragma unroll
        for (int nt = 0; nt < 4; ++nt) {
            const int n = col0 + wn * 64 + nt * 16 + l16;
            const float bon = bo[n];
#pragma unroll
            for (int reg = 0; reg < 4; ++reg) {
                const int m = row0 + wm * 64 + mt * 16 + quad * 4 + reg;
                out[(size_t)m * NP_ + n] = Mi[(size_t)m * NP_ + n] + g * (acc[mt][nt][reg] + bon);
            }
        }
    }
}

extern "C" void kernel_launch(void* const* d_in, const int* in_sizes, int n_in,
                              void* d_out, int out_size, void* d_ws, size_t ws_size,
                              hipStream_t stream)
{
    (void)in_sizes; (void)n_in; (void)out_size;
    const float* Mi   = (const float*)d_in[0];
    const float* Wq   = (const float*)d_in[1];
    const float* Wk   = (const float*)d_in[2];
    const float* Wv   = (const float*)d_in[3];
    const float* Wo   = (const float*)d_in[4];
    const float* bo   = (const float*)d_in[5];
    const float* gate = (const float*)d_in[6];
    float* out  = (float*)d_out;
    float* Aout = out + (size_t)BC_ * NP_;

    // workspace layout (bytes)
    char* p = (char*)d_ws;
    const size_t SZ_W   = (size_t)NP_ * DM_ * 2;     // 512 KB (u16 512x512)
    const size_t SZ_BIG = (size_t)BC_ * DM_ * 2;     // 16 MB (u16 16384x512)
    u16* Wob = (u16*)p; p += SZ_W;
    u16* Wvb = (u16*)p; p += SZ_W;
    u16* Wqh = (u16*)p; p += SZ_W;
    u16* Wql = (u16*)p; p += SZ_W;
    u16* Wkh = (u16*)p; p += SZ_W;
    u16* Wkl = (u16*)p; p += SZ_W;
    u16* Mib = (u16*)p; p += SZ_BIG;
    u16* Mih = (u16*)p; p += SZ_BIG;
    u16* Mil = (u16*)p; p += SZ_BIG;
    u16* Qh  = (u16*)p; p += SZ_BIG;   // [b][h][c][d] f16 hi
    u16* Ql  = (u16*)p; p += SZ_BIG;
    u16* Kh  = (u16*)p; p += SZ_BIG;
    u16* Kl  = (u16*)p; p += SZ_BIG;
    u16* Vb  = (u16*)p; p += SZ_BIG;
    u16* Of  = (u16*)p; p += SZ_BIG;
    float* Sc = (float*)p;

    const size_t fixed = 6 * SZ_W + 9 * SZ_BIG;
    const size_t chunk_bytes = (size_t)H_ * C_ * C_ * 4;   // 32 MB per batch
    size_t availB = (ws_size > fixed) ? (ws_size - fixed) : 0;
    int NB = (int)(availB / chunk_bytes);
    if (NB < 1) NB = 1;
    if (NB > NBMAX) NB = NBMAX;

    w_convert<<<dim3(NP_ * DM_ / 1024, 4), 256, 0, stream>>>(
        Wo, Wv, Wq, Wk, Wob, Wvb, Wqh, Wql, Wkh, Wkl);
    mi_convert<<<dim3((int)((size_t)BC_ * NP_ / 1024)), 256, 0, stream>>>(Mi, Mib, Mih, Mil);

    qk_gemm_mfma<<<dim3(BC_ / 128, DM_ / 128, 2), 256, 0, stream>>>(
        Mih, Mil, Wqh, Wql, Wkh, Wkl, Qh, Ql, Kh, Kl);
    v_gemm_mfma<<<dim3(BC_ / 128, DM_ / 128), 256, 0, stream>>>(Mib, Wvb, Vb);

    for (int b0 = 0; b0 < B_; b0 += NB) {
        const int nb = (B_ - b0 < NB) ? (B_ - b0) : NB;
        const size_t hoff = (size_t)b0 * H_ * C_ * D_;
        score_gemm_mfma<<<dim3(C_ / 128, C_ / 128, nb * 8), 256, 0, stream>>>(
            Qh + hoff, Ql + hoff, Kh + hoff, Kl + hoff, Sc);
        topk_attn<<<dim3(nb * C_), 320, 0, stream>>>(
            Sc, Vb + (size_t)b0 * C_ * DM_, Of + (size_t)b0 * C_ * DM_, Aout, b0);
    }

    final_gemm_mfma<<<dim3(BC_ / 128, NP_ / 128), 256, 0, stream>>>(
        Of, Wob, Mi, bo, gate, out);
}

// Round 11
// 599.346 us; speedup vs baseline: 1.0321x; 1.0321x over previous
//
#include <hip/hip_runtime.h>
#include <hip/hip_bf16.h>

#define B_  16
#define C_  1024
#define NP_ 512
#define DM_ 512
#define H_  8
#define D_  64
#define BC_ 16384

#define PAVG_STRIDE 17
#define NBMAX 4          // S-chunk 128 MB; NBMAX=2 regressed (launch tails > L3 win)
#define FLDS 40          // padded LDS row stride (halfs) for 32-K tiles
#define FLDS2 72         // padded LDS row stride (halfs) for the 64-K score tile
#define STR_C 132        // fp32 LDS stride for the score transpose epilogue

typedef unsigned long long ull;
typedef unsigned short u16;
using short8 = __attribute__((ext_vector_type(8))) short;
using half8  = __attribute__((ext_vector_type(8))) _Float16;
using f32x4  = __attribute__((ext_vector_type(4))) float;

__device__ __forceinline__ u16 f2bf(float x) {
    __hip_bfloat16 h = __float2bfloat16(x);
    return *reinterpret_cast<u16*>(&h);
}
__device__ __forceinline__ float bf2f(u16 v) {
    return __uint_as_float(((unsigned)v) << 16);
}
__device__ __forceinline__ u16 h_bits(_Float16 h) {
    return *reinterpret_cast<u16*>(&h);
}

// ==================== split-f16 MFMA GEMM core ====================
// C(fp32) = A * B^T computed as 4 f16 MFMA passes over (hi+lo) splits.
// Each f16 x f16 product is exact in the fp32 accumulator -> fp32-class
// precision (~2^-23); required: min rank-16/17 gap over 16k avg-rows ~1e-7,
// so do NOT drop the lo*lo pass (3-pass = 2^-22 risks an A-flip).

__device__ __forceinline__ void hsplit_stage(const u16* __restrict__ Ah, const u16* __restrict__ Al,
    const u16* __restrict__ Bh, const u16* __restrict__ Bl,
    int lda, int ldb, int row0, int col0, int k0,
    u16* __restrict__ sAh, u16* __restrict__ sAl,
    u16* __restrict__ sBh, u16* __restrict__ sBl, int tid)
{
#pragma unroll
    for (int rep = 0; rep < 2; ++rep) {
        const int c = tid + rep * 256;
        const int row = c >> 2, kq = (c & 3) * 8;
        const size_t ga = (size_t)(row0 + row) * lda + k0 + kq;
        const size_t gb = (size_t)(col0 + row) * ldb + k0 + kq;
        *(uint4*)(&sAh[row * FLDS + kq]) = *(const uint4*)(Ah + ga);
        *(uint4*)(&sAl[row * FLDS + kq]) = *(const uint4*)(Al + ga);
        *(uint4*)(&sBh[row * FLDS + kq]) = *(const uint4*)(Bh + gb);
        *(uint4*)(&sBl[row * FLDS + kq]) = *(const uint4*)(Bl + gb);
    }
}

__device__ __forceinline__ void hsplit_compute(const u16* __restrict__ sAh, const u16* __restrict__ sAl,
    const u16* __restrict__ sBh, const u16* __restrict__ sBl,
    int lane, int wm, int wn, f32x4 (&acc)[4][4])
{
    const int q8 = (lane >> 4) * 8, l16 = lane & 15;
    half8 bh[4], bl_[4];
#pragma unroll
    for (int nt = 0; nt < 4; ++nt) {
        const int o = (wn * 64 + nt * 16 + l16) * FLDS + q8;
        bh[nt]  = *(const half8*)(&sBh[o]);
        bl_[nt] = *(const half8*)(&sBl[o]);
    }
#pragma unroll
    for (int mt = 0; mt < 4; ++mt) {
        const int o = (wm * 64 + mt * 16 + l16) * FLDS + q8;
        const half8 ah = *(const half8*)(&sAh[o]);
        const half8 al = *(const half8*)(&sAl[o]);
#pragma unroll
        for (int nt = 0; nt < 4; ++nt) {
            acc[mt][nt] = __builtin_amdgcn_mfma_f32_16x16x32_f16(ah, bh[nt],  acc[mt][nt], 0, 0, 0);
            acc[mt][nt] = __builtin_amdgcn_mfma_f32_16x16x32_f16(al, bh[nt],  acc[mt][nt], 0, 0, 0);
            acc[mt][nt] = __builtin_amdgcn_mfma_f32_16x16x32_f16(ah, bl_[nt], acc[mt][nt], 0, 0, 0);
            acc[mt][nt] = __builtin_amdgcn_mfma_f32_16x16x32_f16(al, bl_[nt], acc[mt][nt], 0, 0, 0);
        }
    }
}

// ==================== convert kernels ====================

// merged weight convert: y=0 Wo->bf16, y=1 Wv->bf16, y=2 Wq->f16 hi/lo, y=3 Wk->f16 hi/lo
__global__ __launch_bounds__(256) void w_convert(
    const float* __restrict__ Wo, const float* __restrict__ Wv,
    const float* __restrict__ Wq, const float* __restrict__ Wk,
    u16* __restrict__ Wob, u16* __restrict__ Wvb,
    u16* __restrict__ Wqh, u16* __restrict__ Wql,
    u16* __restrict__ Wkh, u16* __restrict__ Wkl)
{
    const int i = (blockIdx.x * 256 + threadIdx.x) * 4;
    const int y = blockIdx.y;
    if (y < 2) {
        const float* X = (y == 0) ? Wo : Wv;
        u16* Dp = (y == 0) ? Wob : Wvb;
        const float4 v = *(const float4*)(X + i);
        ushort4 o;
        o.x = f2bf(v.x); o.y = f2bf(v.y); o.z = f2bf(v.z); o.w = f2bf(v.w);
        *(ushort4*)(Dp + i) = o;
    } else {
        const float* X = (y == 2) ? Wq : Wk;
        u16* Hh = (y == 2) ? Wqh : Wkh;
        u16* Hl = (y == 2) ? Wql : Wkl;
        const float4 v = *(const float4*)(X + i);
        ushort4 oh, ol;
        {
            _Float16 h = (_Float16)v.x; oh.x = h_bits(h); ol.x = h_bits((_Float16)(v.x - (float)h));
        }{
            _Float16 h = (_Float16)v.y; oh.y = h_bits(h); ol.y = h_bits((_Float16)(v.y - (float)h));
        }{
            _Float16 h = (_Float16)v.z; oh.z = h_bits(h); ol.z = h_bits((_Float16)(v.z - (float)h));
        }{
            _Float16 h = (_Float16)v.w; oh.w = h_bits(h); ol.w = h_bits((_Float16)(v.w - (float)h));
        }
        *(ushort4*)(Hh + i) = oh;
        *(ushort4*)(Hl + i) = ol;
    }
}

// Mi -> bf16 (for V path) + f16 hi/lo (for Q/K path) in one read pass
__global__ __launch_bounds__(256) void mi_convert(const float* __restrict__ X,
    u16* __restrict__ Bb, u16* __restrict__ Hh, u16* __restrict__ Hl)
{
    const int i = (blockIdx.x * 256 + threadIdx.x) * 4;
    const float4 v = *(const float4*)(X + i);
    ushort4 ob, oh, ol;
    {
        _Float16 h = (_Float16)v.x; ob.x = f2bf(v.x); oh.x = h_bits(h); ol.x = h_bits((_Float16)(v.x - (float)h));
    }{
        _Float16 h = (_Float16)v.y; ob.y = f2bf(v.y); oh.y = h_bits(h); ol.y = h_bits((_Float16)(v.y - (float)h));
    }{
        _Float16 h = (_Float16)v.z; ob.z = f2bf(v.z); oh.z = h_bits(h); ol.z = h_bits((_Float16)(v.z - (float)h));
    }{
        _Float16 h = (_Float16)v.w; ob.w = f2bf(v.w); oh.w = h_bits(h); ol.w = h_bits((_Float16)(v.w - (float)h));
    }
    *(ushort4*)(Bb + i) = ob;
    *(ushort4*)(Hh + i) = oh;
    *(ushort4*)(Hl + i) = ol;
}

// ==================== kernel 1: Q/K projections via split-f16 MFMA ====================
__global__ __launch_bounds__(256) void qk_gemm_mfma(
    const u16* __restrict__ Mih, const u16* __restrict__ Mil,
    const u16* __restrict__ Wqh, const u16* __restrict__ Wql,
    const u16* __restrict__ Wkh, const u16* __restrict__ Wkl,
    u16* __restrict__ Qh, u16* __restrict__ Ql,
    u16* __restrict__ Kh, u16* __restrict__ Kl)
{
    __shared__ u16 sAh[128 * FLDS];
    __shared__ u16 sAl[128 * FLDS];
    __shared__ u16 sBh[128 * FLDS];
    __shared__ u16 sBl[128 * FLDS];

    const int tid = threadIdx.x, lane = tid & 63, w = tid >> 6;
    const int wm = w >> 1, wn = w & 1;
    const int z = blockIdx.z;
    const u16* Bh = z ? Wkh : Wqh;
    const u16* Bl = z ? Wkl : Wql;
    u16* outH = z ? Kh : Qh;
    u16* outL = z ? Kl : Ql;
    const int row0 = blockIdx.x * 128, col0 = blockIdx.y * 128;

    f32x4 acc[4][4];
#pragma unroll
    for (int mt = 0; mt < 4; ++mt)
#pragma unroll
        for (int nt = 0; nt < 4; ++nt)
            acc[mt][nt] = (f32x4){0.f, 0.f, 0.f, 0.f};

    for (int k0 = 0; k0 < NP_; k0 += 32) {
        hsplit_stage(Mih, Mil, Bh, Bl, NP_, NP_, row0, col0, k0, sAh, sAl, sBh, sBl, tid);
        __syncthreads();
        hsplit_compute(sAh, sAl, sBh, sBl, lane, wm, wn, acc);
        __syncthreads();
    }

    const int quad = lane >> 4, l16 = lane & 15;
#pragma unroll
    for (int mt = 0; mt < 4; ++mt)
#pragma unroll
        for (int nt = 0; nt < 4; ++nt) {
            const int n = col0 + wn * 64 + nt * 16 + l16;
            const int hh = n >> 6, dd = n & 63;
#pragma unroll
            for (int reg = 0; reg < 4; ++reg) {
                const int m = row0 + wm * 64 + mt * 16 + quad * 4 + reg;
                const int bl = m >> 10, c = m & 1023;
                const size_t idx = ((size_t)(bl * 8 + hh) * C_ + c) * D_ + dd;
                const float v = acc[mt][nt][reg];
                const _Float16 vh = (_Float16)v;
                outH[idx] = h_bits(vh);
                outL[idx] = h_bits((_Float16)(v - (float)vh));
            }
        }
}

// ==================== kernel 2: scores via split-f16 MFMA, single-stage BK=64 ====================
// Epilogue: transpose acc through (reused) LDS so the 128 MB S-write goes out as
// fully-coalesced float4 row stores (2x512B segments per wave-instr) instead of
// the MFMA-layout scalar stores (4x64B segments). Bit-identical values.
__global__ __launch_bounds__(256) void score_gemm_mfma(
    const u16* __restrict__ Qh, const u16* __restrict__ Ql,
    const u16* __restrict__ Kh, const u16* __restrict__ Kl,
    float* __restrict__ S)
{
    __shared__ u16 smem[4 * 128 * FLDS2];   // 73728 B; also reused as 128x132 fp32 (67584 B)
    u16* sAh = smem;
    u16* sAl = smem + 128 * FLDS2;
    u16* sBh = smem + 2 * 128 * FLDS2;
    u16* sBl = smem + 3 * 128 * FLDS2;

    const int tid = threadIdx.x, lane = tid & 63, w = tid >> 6;
    const int wm = w >> 1, wn = w & 1;
    const int z = blockIdx.z;
    const size_t off = (size_t)z * C_ * D_;
    const u16* Ah = Qh + off;  const u16* Al = Ql + off;
    const u16* Bh = Kh + off;  const u16* Bl = Kl + off;
    float* Cp = S + (size_t)z * C_ * C_;
    const int row0 = blockIdx.x * 128, col0 = blockIdx.y * 128;

    f32x4 acc[4][4];
#pragma unroll
    for (int mt = 0; mt < 4; ++mt)
#pragma unroll
        for (int nt = 0; nt < 4; ++nt)
            acc[mt][nt] = (f32x4){0.f, 0.f, 0.f, 0.f};

    // stage all K=64 (8 uint4-chunks per 128-B row; 1024 chunks per plane)
#pragma unroll
    for (int rep = 0; rep < 4; ++rep) {
        const int c = tid + rep * 256;
        const int row = c >> 3, kq = (c & 7) * 8;
        const size_t ga = (size_t)(row0 + row) * D_ + kq;
        const size_t gb = (size_t)(col0 + row) * D_ + kq;
        *(uint4*)(&sAh[row * FLDS2 + kq]) = *(const uint4*)(Ah + ga);
        *(uint4*)(&sAl[row * FLDS2 + kq]) = *(const uint4*)(Al + ga);
        *(uint4*)(&sBh[row * FLDS2 + kq]) = *(const uint4*)(Bh + gb);
        *(uint4*)(&sBl[row * FLDS2 + kq]) = *(const uint4*)(Bl + gb);
    }
    __syncthreads();

    const int q8 = (lane >> 4) * 8, l16 = lane & 15;
#pragma unroll
    for (int ks = 0; ks < 2; ++ks) {
        const int kof = ks * 32 + q8;
        half8 bh[4], bl_[4];
#pragma unroll
        for (int nt = 0; nt < 4; ++nt) {
            const int o = (wn * 64 + nt * 16 + l16) * FLDS2 + kof;
            bh[nt]  = *(const half8*)(&sBh[o]);
            bl_[nt] = *(const half8*)(&sBl[o]);
        }
#pragma unroll
        for (int mt = 0; mt < 4; ++mt) {
            const int o = (wm * 64 + mt * 16 + l16) * FLDS2 + kof;
            const half8 ah = *(const half8*)(&sAh[o]);
            const half8 al = *(const half8*)(&sAl[o]);
#pragma unroll
            for (int nt = 0; nt < 4; ++nt) {
                acc[mt][nt] = __builtin_amdgcn_mfma_f32_16x16x32_f16(ah, bh[nt],  acc[mt][nt], 0, 0, 0);
                acc[mt][nt] = __builtin_amdgcn_mfma_f32_16x16x32_f16(al, bh[nt],  acc[mt][nt], 0, 0, 0);
                acc[mt][nt] = __builtin_amdgcn_mfma_f32_16x16x32_f16(ah, bl_[nt], acc[mt][nt], 0, 0, 0);
                acc[mt][nt] = __builtin_amdgcn_mfma_f32_16x16x32_f16(al, bl_[nt], acc[mt][nt], 0, 0, 0);
            }
        }
    }

    // ---- transpose epilogue ----
    __syncthreads();                       // all LDS staging reads done
    float* st = (float*)smem;              // 128 x STR_C fp32 tile
    const int quad = lane >> 4;
#pragma unroll
    for (int mt = 0; mt < 4; ++mt)
#pragma unroll
        for (int nt = 0; nt < 4; ++nt) {
            const int n = wn * 64 + nt * 16 + l16;
#pragma unroll
            for (int reg = 0; reg < 4; ++reg) {
                const int m = wm * 64 + mt * 16 + quad * 4 + reg;
                st[m * STR_C + n] = acc[mt][nt][reg] * 0.125f;
            }
        }
    __syncthreads();
#pragma unroll
    for (int pass = 0; pass < 16; ++pass) {
        const int idx = pass * 256 + tid;
        const int row = idx >> 5;
        const int c4  = (idx & 31) << 2;
        const float4 v = *(const float4*)&st[row * STR_C + c4];
        *(float4*)(Cp + (size_t)(row0 + row) * C_ + col0 + c4) = v;
    }
}

// ==================== kernel 1b: V projection via bf16 MFMA ====================
__global__ __launch_bounds__(256) void v_gemm_mfma(const u16* __restrict__ Mib,
    const u16* __restrict__ Wvb, u16* __restrict__ Vb)
{
    __shared__ u16 As[128 * FLDS];
    __shared__ u16 Bs[128 * FLDS];
    const int tid = threadIdx.x, lane = tid & 63, w = tid >> 6;
    const int wm = w >> 1, wn = w & 1;
    const int row0 = blockIdx.x * 128, col0 = blockIdx.y * 128;

    f32x4 acc[4][4];
#pragma unroll
    for (int mt = 0; mt < 4; ++mt)
#pragma unroll
        for (int nt = 0; nt < 4; ++nt)
            acc[mt][nt] = (f32x4){0.f, 0.f, 0.f, 0.f};

    const int q8 = (lane >> 4) * 8, l16 = lane & 15;
    for (int k0 = 0; k0 < NP_; k0 += 32) {
#pragma unroll
        for (int rep = 0; rep < 2; ++rep) {
            const int c = tid + rep * 256;
            const int row = c >> 2, kq = (c & 3) * 8;
            *(uint4*)(&As[row * FLDS + kq]) = *(const uint4*)(Mib + (size_t)(row0 + row) * NP_ + k0 + kq);
            *(uint4*)(&Bs[row * FLDS + kq]) = *(const uint4*)(Wvb + (size_t)(col0 + row) * NP_ + k0 + kq);
        }
        __syncthreads();
        short8 a[4], bfr[4];
#pragma unroll
        for (int mt = 0; mt < 4; ++mt)
            a[mt] = *(const short8*)(&As[(wm * 64 + mt * 16 + l16) * FLDS + q8]);
#pragma unroll
        for (int nt = 0; nt < 4; ++nt)
            bfr[nt] = *(const short8*)(&Bs[(wn * 64 + nt * 16 + l16) * FLDS + q8]);
#pragma unroll
        for (int mt = 0; mt < 4; ++mt)
#pragma unroll
            for (int nt = 0; nt < 4; ++nt)
                acc[mt][nt] = __builtin_amdgcn_mfma_f32_16x16x32_bf16(a[mt], bfr[nt], acc[mt][nt], 0, 0, 0);
        __syncthreads();
    }
    const int quad = lane >> 4;
#pragma unroll
    for (int mt = 0; mt < 4; ++mt)
#pragma unroll
        for (int nt = 0; nt < 4; ++nt) {
            const int n = col0 + wn * 64 + nt * 16 + l16;
#pragma unroll
            for (int reg = 0; reg < 4; ++reg) {
                const int m = row0 + wm * 64 + mt * 16 + quad * 4 + reg;
                Vb[(size_t)m * DM_ + n] = f2bf(acc[mt][nt][reg]);
            }
        }
}

// ==================== top-k machinery ====================
// key = (monotone(value) << 32) | (1023 - j): distinct keys, ties -> smallest j
// (matches jax.lax.top_k). tau via dual-interleaved ballot radix TRUNCATED at
// bit 12 (tau' <= exact 16th-largest lane-max; candidate superset, exact sort
// downstream). 32-wide bitonic fast path when candidates <= 32 (common case).

__device__ __forceinline__ ull pack1(float f, int j) {
    unsigned b = __float_as_uint(f);
    unsigned u = b ^ ((unsigned)((int)b >> 31) | 0x80000000u);
    return ((ull)u << 32) | (unsigned)(1023 - j);
}
__device__ __forceinline__ float unpack_val(ull e) {
    unsigned u = (unsigned)(e >> 32);
    unsigned b = u ^ ((u & 0x80000000u) ? 0x80000000u : 0xFFFFFFFFu);
    return __uint_as_float(b);
}
__device__ __forceinline__ int unpack_j(ull e) {
    return 1023 - (int)(e & 0xFFFFFFFFu);
}
__device__ __forceinline__ unsigned mono32(float f) {
    unsigned b = __float_as_uint(f);
    return b ^ ((unsigned)((int)b >> 31) | 0x80000000u);
}
__device__ __forceinline__ float mono32_inv(unsigned u) {
    unsigned b = u ^ ((u & 0x80000000u) ? 0x80000000u : 0xFFFFFFFFu);
    return __uint_as_float(b);
}

// truncated (20-step) lower bound on the 16th-largest of the 64 lane keys
__device__ __forceinline__ unsigned radix16_u32(unsigned k)
{
    unsigned p = 0u;
#pragma unroll
    for (int b = 31; b >= 12; --b) {
        const unsigned t = p | (1u << b);
        if (__popcll(__ballot(k >= t)) >= 16) p = t;
    }
    return p;
}

// dual-interleaved truncated version: both chains advance each iteration
__device__ __forceinline__ void radix16_dual_u32(unsigned kA, unsigned kB,
                                                 unsigned &pA, unsigned &pB)
{
    pA = 0u; pB = 0u;
#pragma unroll
    for (int b = 31; b >= 12; --b) {
        const unsigned tA = pA | (1u << b);
        const unsigned tB = pB | (1u << b);
        const ull mA = __ballot(kA >= tA);
        const ull mB = __ballot(kB >= tB);
        if (__popcll(mA) >= 16) pA = tA;
        if (__popcll(mB) >= 16) pB = tB;
    }
}

// ---- single-chain top-16 (avg-scores wave). Radix tau + bitonic cand sort. ----
__device__ __forceinline__ void topk16_fast(float (&f)[16], const int lane,
                                            ull* candw, ull (&out)[16])
{
    float mv = f[0];
#pragma unroll
    for (int r = 1; r < 16; ++r) mv = fmaxf(mv, f[r]);
    const float tau = mono32_inv(radix16_u32(mono32(mv)));

    unsigned msk = 0u;
#pragma unroll
    for (int r = 0; r < 16; ++r) msk |= (f[r] >= tau) ? (1u << r) : 0u;
    const int cnt = __popc(msk);
    int incl = cnt;
#pragma unroll
    for (int off = 1; off < 64; off <<= 1) {
        const int t = __shfl_up(incl, off);
        incl += (lane >= off) ? t : 0;
    }
    const int total = __shfl(incl, 63);

    if (total <= 64) {
        int ofs = incl - cnt;
        unsigned m = msk;
        while (m) {
            const int r = __ffs(m) - 1;
            m &= m - 1;
            candw[ofs++] = pack1(f[r], (lane << 4) + r);
        }
        ull e = candw[lane];
        if (lane >= total) e = 0ull;
        if (total <= 32) {
#pragma unroll
            for (int k = 2; k <= 32; k <<= 1) {
#pragma unroll
                for (int j = k >> 1; j > 0; j >>= 1) {
                    const ull p = __shfl_xor(e, j);
                    const bool kmax = ((lane & k) == 0) == ((lane & j) == 0);
                    if ((p > e) == kmax) e = p;
                }
            }
        } else {
#pragma unroll
            for (int k = 2; k <= 64; k <<= 1) {
#pragma unroll
                for (int j = k >> 1; j > 0; j >>= 1) {
                    const ull p = __shfl_xor(e, j);
                    const bool kmax = ((lane & k) == 0) == ((lane & j) == 0);
                    if ((p > e) == kmax) e = p;
                }
            }
        }
#pragma unroll
        for (int t = 0; t < 16; ++t) out[t] = __shfl(e, t);
    } else {
        for (int it = 0; it < 16; ++it) {
            float bv = f[0]; int bj = lane << 4;
#pragma unroll
            for (int r = 1; r < 16; ++r)
                if (f[r] > bv) { bv = f[r]; bj = (lane << 4) + r; }
#pragma unroll
            for (int off = 32; off >= 1; off >>= 1) {
                const float ov = __shfl_xor(bv, off);
                const int   oj = __shfl_xor(bj, off);
                if (ov > bv || (ov == bv && oj < bj)) { bv = ov; bj = oj; }
            }
            out[it] = pack1(bv, bj);
            if ((bj >> 4) == lane) f[bj & 15] = -3.402823466e38f;
        }
    }
}

// ---- fallback serial selection; lane t (t<16) ends holding rank-t element ----
__device__ __forceinline__ ull topk16_serial(float (&f)[16], const int lane)
{
    ull e = 0ull;
    for (int it = 0; it < 16; ++it) {
        float bv = f[0]; int bj = lane << 4;
#pragma unroll
        for (int r = 1; r < 16; ++r)
            if (f[r] > bv) { bv = f[r]; bj = (lane << 4) + r; }
#pragma unroll
        for (int off = 32; off >= 1; off >>= 1) {
            const float ov = __shfl_xor(bv, off);
            const int   oj = __shfl_xor(bj, off);
            if (ov > bv || (ov == bv && oj < bj)) { bv = ov; bj = oj; }
        }
        if (lane == it) e = pack1(bv, bj);
        if ((bj >> 4) == lane) f[bj & 15] = -3.402823466e38f;
    }
    return e;
}

// ---- dual-chain top-16 (round-2/4 proven structure; truncated dual radix tau;
// 32-wide bitonic fast path when both chains have <=32 candidates) ----
__device__ __forceinline__ void topk16_dual(float (&fA)[16], float (&fB)[16],
                                            const int lane, ull* cwA, ull* cwB,
                                            ull &eA, ull &eB)
{
    float mA = fA[0], mB = fB[0];
#pragma unroll
    for (int r = 1; r < 16; ++r) { mA = fmaxf(mA, fA[r]); mB = fmaxf(mB, fB[r]); }
    unsigned pA, pB;
    radix16_dual_u32(mono32(mA), mono32(mB), pA, pB);
    const float tauA = mono32_inv(pA);
    const float tauB = mono32_inv(pB);

    unsigned mskA = 0u, mskB = 0u;
#pragma unroll
    for (int r = 0; r < 16; ++r) {
        mskA |= (fA[r] >= tauA) ? (1u << r) : 0u;
        mskB |= (fB[r] >= tauB) ? (1u << r) : 0u;
    }
    const int cntA = __popc(mskA), cntB = __popc(mskB);
    int inclA = cntA, inclB = cntB;
#pragma unroll
    for (int off = 1; off < 64; off <<= 1) {
        const int tA = __shfl_up(inclA, off);
        const int tB = __shfl_up(inclB, off);
        inclA += (lane >= off) ? tA : 0;
        inclB += (lane >= off) ? tB : 0;
    }
    const int totalA = __shfl(inclA, 63);
    const int totalB = __shfl(inclB, 63);

    if (totalA <= 64) {
        int ofs = inclA - cntA;
        unsigned m = mskA;
        while (m) {
            const int r = __ffs(m) - 1;
            m &= m - 1;
            cwA[ofs++] = pack1(fA[r], (lane << 4) + r);
        }
    }
    if (totalB <= 64) {
        int ofs = inclB - cntB;
        unsigned m = mskB;
        while (m) {
            const int r = __ffs(m) - 1;
            m &= m - 1;
            cwB[ofs++] = pack1(fB[r], (lane << 4) + r);
        }
    }
    eA = (totalA <= 64 && lane < totalA) ? cwA[lane] : 0ull;
    eB = (totalB <= 64 && lane < totalB) ? cwB[lane] : 0ull;
    if (totalA <= 32 && totalB <= 32) {
#pragma unroll
        for (int k = 2; k <= 32; k <<= 1) {
#pragma unroll
            for (int j = k >> 1; j > 0; j >>= 1) {
                const ull pAx = __shfl_xor(eA, j);
                const ull pBx = __shfl_xor(eB, j);
                const bool kmax = ((lane & k) == 0) == ((lane & j) == 0);
                if ((pAx > eA) == kmax) eA = pAx;
                if ((pBx > eB) == kmax) eB = pBx;
            }
        }
    } else {
#pragma unroll
        for (int k = 2; k <= 64; k <<= 1) {
#pragma unroll
            for (int j = k >> 1; j > 0; j >>= 1) {
                const ull pAx = __shfl_xor(eA, j);
                const ull pBx = __shfl_xor(eB, j);
                const bool kmax = ((lane & k) == 0) == ((lane & j) == 0);
                if ((pAx > eA) == kmax) eA = pAx;
                if ((pBx > eB) == kmax) eB = pBx;
            }
        }
    }
    if (totalA > 64) eA = topk16_serial(fA, lane);
    if (totalB > 64) eB = topk16_serial(fB, lane);
}

__device__ __forceinline__ void attn_out(const ull e, const u16* __restrict__ V,
                                         int bl, int i, int h, int lane,
                                         u16* __restrict__ O)
{
    float vals[16]; int jl[16];
#pragma unroll
    for (int t = 0; t < 16; ++t) {
        const ull et = __shfl(e, t);
        vals[t] = unpack_val(et);
        jl[t]   = unpack_j(et);
    }
    const float mx = vals[0];
    float wv[16];
    float Z = 0.0f;
#pragma unroll
    for (int t = 0; t < 16; ++t) { wv[t] = __expf(vals[t] - mx); Z += wv[t]; }
    const float inv = 1.0f / Z;
#pragma unroll
    for (int t = 0; t < 16; ++t) wv[t] *= inv;
    float o = 0.0f;
#pragma unroll
    for (int t = 0; t < 16; ++t)
        o = fmaf(wv[t], bf2f(V[((size_t)(bl * C_ + jl[t])) * DM_ + h * D_ + lane]), o);
    O[((size_t)(bl * C_ + i)) * DM_ + h * D_ + lane] = f2bf(o);
}

// ---- kernel 3: per-row topk + softmax + sparse AV(bf16) + A output ----
// 320 threads: waves 0-3 handle the 8 attention heads (dual-chain, 2 each);
// wave 4 does the avg-scores top-16 concurrently, writes A row directly.
__global__ __launch_bounds__(320) void topk_attn(const float* __restrict__ S,
    const u16* __restrict__ V, u16* __restrict__ O,
    float* __restrict__ Aout, int b0)
{
    __shared__ float pavg[4 * 64 * PAVG_STRIDE];
    __shared__ ull   cand[4][2][64];
    __shared__ ull   candA[64];

    const int tid = threadIdx.x, lane = tid & 63, w = tid >> 6;
    const int rb = blockIdx.x, bl = rb >> 10, i = rb & 1023;
    const int b = b0 + bl;

    float f1[16], f2[16];
    if (w < 4) {
        const float* r1 = S + ((size_t)(bl * 8 + w) * C_ + i) * C_ + lane * 16;
        const float* r2 = S + ((size_t)(bl * 8 + w + 4) * C_ + i) * C_ + lane * 16;
#pragma unroll
        for (int q = 0; q < 4; ++q) {
            const float4 x = *(const float4*)(r1 + q * 4);
            f1[q * 4 + 0] = x.x; f1[q * 4 + 1] = x.y; f1[q * 4 + 2] = x.z; f1[q * 4 + 3] = x.w;
            const float4 y = *(const float4*)(r2 + q * 4);
            f2[q * 4 + 0] = y.x; f2[q * 4 + 1] = y.y; f2[q * 4 + 2] = y.z; f2[q * 4 + 3] = y.w;
        }
        float* pw = pavg + w * 64 * PAVG_STRIDE + lane * PAVG_STRIDE;
#pragma unroll
        for (int r = 0; r < 16; ++r) pw[r] = f1[r] + f2[r];
    }
    __syncthreads();

    if (w < 4) {
        ull eA, eB;
        topk16_dual(f1, f2, lane, cand[w][0], cand[w][1], eA, eB);
        attn_out(eA, V, bl, i, w,     lane, O);
        attn_out(eB, V, bl, i, w + 4, lane, O);
    } else {
        float fa[16];
#pragma unroll
        for (int r = 0; r < 16; ++r) {
            fa[r] = pavg[0 * 64 * PAVG_STRIDE + lane * PAVG_STRIDE + r]
                  + pavg[1 * 64 * PAVG_STRIDE + lane * PAVG_STRIDE + r]
                  + pavg[2 * 64 * PAVG_STRIDE + lane * PAVG_STRIDE + r]
                  + pavg[3 * 64 * PAVG_STRIDE + lane * PAVG_STRIDE + r];
        }
        ull top[16];
        topk16_fast(fa, lane, candA, top);
        unsigned mybits = 0u;
#pragma unroll
        for (int t = 0; t < 16; ++t) {
            const int j = unpack_j(top[t]);
            if ((j >> 4) == lane) mybits |= 1u << (j & 15);
        }
        float* arow = Aout + ((size_t)(b * C_ + i)) * C_ + lane * 16;
#pragma unroll
        for (int q = 0; q < 4; ++q) {
            float4 o4;
            o4.x = ((mybits >> (q * 4 + 0)) & 1u) ? 1.0f : 0.0f;
            o4.y = ((mybits >> (q * 4 + 1)) & 1u) ? 1.0f : 0.0f;
            o4.z = ((mybits >> (q * 4 + 2)) & 1u) ? 1.0f : 0.0f;
            o4.w = ((mybits >> (q * 4 + 3)) & 1u) ? 1.0f : 0.0f;
            *(float4*)(arow + q * 4) = o4;
        }
    }
}

// ---- kernel 4: MFMA bf16: delta = O @ Wo^T + bo ; M_tilde = M + gate*delta ----
__global__ __launch_bounds__(256) void final_gemm_mfma(const u16* __restrict__ O,
    const u16* __restrict__ Wob, const float* __restrict__ Mi,
    const float* __restrict__ bo, const float* __restrict__ gatep,
    float* __restrict__ out)
{
    __shared__ u16 As[128 * FLDS];
    __shared__ u16 Bs[128 * FLDS];
    const int tid = threadIdx.x, lane = tid & 63, w = tid >> 6;
    const int wm = w >> 1, wn = w & 1;
    const int row0 = blockIdx.x * 128, col0 = blockIdx.y * 128;

    f32x4 acc[4][4];
#pragma unroll
    for (int mt = 0; mt < 4; ++mt)
#pragma unroll
        for (int nt = 0; nt < 4; ++nt)
            acc[mt][nt] = (f32x4){0.f, 0.f, 0.f, 0.f};

    const int q8 = (lane >> 4) * 8, l16 = lane & 15;
    for (int k0 = 0; k0 < DM_; k0 += 32) {
#pragma unroll
        for (int rep = 0; rep < 2; ++rep) {
            const int c = tid + rep * 256;
            const int row = c >> 2, kq = (c & 3) * 8;
            *(uint4*)(&As[row * FLDS + kq]) = *(const uint4*)(O   + (size_t)(row0 + row) * DM_ + k0 + kq);
            *(uint4*)(&Bs[row * FLDS + kq]) = *(const uint4*)(Wob + (size_t)(col0 + row) * DM_ + k0 + kq);
        }
        __syncthreads();
        short8 a[4], bfr[4];
#pragma unroll
        for (int mt = 0; mt < 4; ++mt)
            a[mt] = *(const short8*)(&As[(wm * 64 + mt * 16 + l16) * FLDS + q8]);
#pragma unroll
        for (int nt = 0; nt < 4; ++nt)
            bfr[nt] = *(const short8*)(&Bs[(wn * 64 + nt * 16 + l16) * FLDS + q8]);
#pragma unroll
        for (int mt = 0; mt < 4; ++mt)
#pragma unroll
            for (int nt = 0; nt < 4; ++nt)
                acc[mt][nt] = __builtin_amdgcn_mfma_f32_16x16x32_bf16(a[mt], bfr[nt], acc[mt][nt], 0, 0, 0);
        __syncthreads();
    }

    const float g = gatep[0];
    const int quad = lane >> 4;
#pragma unroll
    for (int mt = 0; mt < 4; ++mt) {
#pragma unroll
        for (int nt = 0; nt < 4; ++nt) {
            const int n = col0 + wn * 64 + nt * 16 + l16;
            const float bon = bo[n];
#pragma unroll
            for (int reg = 0; reg < 4; ++reg) {
                const int m = row0 + wm * 64 + mt * 16 + quad * 4 + reg;
                out[(size_t)m * NP_ + n] = Mi[(size_t)m * NP_ + n] + g * (acc[mt][nt][reg] + bon);
            }
        }
    }
}

extern "C" void kernel_launch(void* const* d_in, const int* in_sizes, int n_in,
                              void* d_out, int out_size, void* d_ws, size_t ws_size,
                              hipStream_t stream)
{
    (void)in_sizes; (void)n_in; (void)out_size;
    const float* Mi   = (const float*)d_in[0];
    const float* Wq   = (const float*)d_in[1];
    const float* Wk   = (const float*)d_in[2];
    const float* Wv   = (const float*)d_in[3];
    const float* Wo   = (const float*)d_in[4];
    const float* bo   = (const float*)d_in[5];
    const float* gate = (const float*)d_in[6];
    float* out  = (float*)d_out;
    float* Aout = out + (size_t)BC_ * NP_;

    // workspace layout (bytes)
    char* p = (char*)d_ws;
    const size_t SZ_W   = (size_t)NP_ * DM_ * 2;     // 512 KB (u16 512x512)
    const size_t SZ_BIG = (size_t)BC_ * DM_ * 2;     // 16 MB (u16 16384x512)
    u16* Wob = (u16*)p; p += SZ_W;
    u16* Wvb = (u16*)p; p += SZ_W;
    u16* Wqh = (u16*)p; p += SZ_W;
    u16* Wql = (u16*)p; p += SZ_W;
    u16* Wkh = (u16*)p; p += SZ_W;
    u16* Wkl = (u16*)p; p += SZ_W;
    u16* Mib = (u16*)p; p += SZ_BIG;
    u16* Mih = (u16*)p; p += SZ_BIG;
    u16* Mil = (u16*)p; p += SZ_BIG;
    u16* Qh  = (u16*)p; p += SZ_BIG;   // [b][h][c][d] f16 hi
    u16* Ql  = (u16*)p; p += SZ_BIG;
    u16* Kh  = (u16*)p; p += SZ_BIG;
    u16* Kl  = (u16*)p; p += SZ_BIG;
    u16* Vb  = (u16*)p; p += SZ_BIG;
    u16* Of  = (u16*)p; p += SZ_BIG;
    float* Sc = (float*)p;

    const size_t fixed = 6 * SZ_W + 9 * SZ_BIG;
    const size_t chunk_bytes = (size_t)H_ * C_ * C_ * 4;   // 32 MB per batch
    size_t availB = (ws_size > fixed) ? (ws_size - fixed) : 0;
    int NB = (int)(availB / chunk_bytes);
    if (NB < 1) NB = 1;
    if (NB > NBMAX) NB = NBMAX;

    w_convert<<<dim3(NP_ * DM_ / 1024, 4), 256, 0, stream>>>(
        Wo, Wv, Wq, Wk, Wob, Wvb, Wqh, Wql, Wkh, Wkl);
    mi_convert<<<dim3((int)((size_t)BC_ * NP_ / 1024)), 256, 0, stream>>>(Mi, Mib, Mih, Mil);

    qk_gemm_mfma<<<dim3(BC_ / 128, DM_ / 128, 2), 256, 0, stream>>>(
        Mih, Mil, Wqh, Wql, Wkh, Wkl, Qh, Ql, Kh, Kl);
    v_gemm_mfma<<<dim3(BC_ / 128, DM_ / 128), 256, 0, stream>>>(Mib, Wvb, Vb);

    for (int b0 = 0; b0 < B_; b0 += NB) {
        const int nb = (B_ - b0 < NB) ? (B_ - b0) : NB;
        const size_t hoff = (size_t)b0 * H_ * C_ * D_;
        score_gemm_mfma<<<dim3(C_ / 128, C_ / 128, nb * 8), 256, 0, stream>>>(
            Qh + hoff, Ql + hoff, Kh + hoff, Kl + hoff, Sc);
        topk_attn<<<dim3(nb * C_), 320, 0, stream>>>(
            Sc, Vb + (size_t)b0 * C_ * DM_, Of + (size_t)b0 * C_ * DM_, Aout, b0);
    }

    final_gemm_mfma<<<dim3(BC_ / 128, NP_ / 128), 256, 0, stream>>>(
        Of, Wob, Mi, bo, gate, out);
}